// Round 3
// baseline (680.496 us; speedup 1.0000x reference)
//
#include <hip/hip_runtime.h>
#include <hip/hip_bf16.h>

// Problem constants
#define OUT_F 11008   // N
#define IN_F  4096    // K
#define M_DIM 4096    // 4 * 1024

typedef __attribute__((ext_vector_type(8))) short bf16x8;          // MFMA A/B frag
typedef __attribute__((ext_vector_type(4))) float f32x4;           // MFMA C/D frag
typedef __attribute__((ext_vector_type(8))) unsigned short us8;    // 16B of bf16 bits

// ---------------------------------------------------------------------------
// Kernel 1 (fused prep): blocks [0,8192) convert x fp32->bf16 (8 elems/thr);
// blocks [8192, 8192+11008) unpack 2-bit weights -> bf16 [OUT_F][IN_F].
// ---------------------------------------------------------------------------
__device__ __forceinline__ unsigned short f2bf_rne(float f) {
    unsigned u = __builtin_bit_cast(unsigned, f);
    u += 0x7fffu + ((u >> 16) & 1u);
    return (unsigned short)(u >> 16);
}

__global__ void prep_kernel(const float* __restrict__ x,
                            unsigned short* __restrict__ xb,
                            const int* __restrict__ pw,
                            unsigned short* __restrict__ wb) {
    if (blockIdx.x < 8192) {
        size_t i = ((size_t)blockIdx.x * blockDim.x + threadIdx.x) * 8;
        float4 a = *(const float4*)(x + i);
        float4 b = *(const float4*)(x + i + 4);
        us8 o;
        o[0] = f2bf_rne(a.x); o[1] = f2bf_rne(a.y);
        o[2] = f2bf_rne(a.z); o[3] = f2bf_rne(a.w);
        o[4] = f2bf_rne(b.x); o[5] = f2bf_rne(b.y);
        o[6] = f2bf_rne(b.z); o[7] = f2bf_rne(b.w);
        *(us8*)(xb + i) = o;
    } else {
        size_t i = ((size_t)(blockIdx.x - 8192)) * blockDim.x + threadIdx.x;
        int4 v = ((const int4*)pw)[i];
        const unsigned long long LUT = 0x40003F800000BF80ull;
        us8 o0, o1;
#pragma unroll
        for (int j = 0; j < 4; j++) {
            o0[j]     = (unsigned short)(LUT >> (((v.x >> (2 * j)) & 3) * 16));
            o0[4 + j] = (unsigned short)(LUT >> (((v.y >> (2 * j)) & 3) * 16));
            o1[j]     = (unsigned short)(LUT >> (((v.z >> (2 * j)) & 3) * 16));
            o1[4 + j] = (unsigned short)(LUT >> (((v.w >> (2 * j)) & 3) * 16));
        }
        ((us8*)wb)[i * 2]     = o0;
        ((us8*)wb)[i * 2 + 1] = o1;
    }
}

// ---------------------------------------------------------------------------
// Kernel 2: bf16 GEMM, 128x256 tile, BK=32, 8 waves of 64x64, 2 blocks/CU.
//
// WHY this shape (round-3 theory): with one 8-wave barrier group per CU,
// phase structure serializes LDS-read bursts with MFMA bursts -> 42% MfmaUtil
// ceiling (round-2 null on deeper vmcnt proved latency isn't the limiter).
// Two INDEPENDENT blocks per CU drift out of phase, so block0's ds_read/
// barrier phases overlap block1's MFMA phases (m114 wave-level overlap).
// Requires per-wave regs <=128 (pool 512/SIMD) => 64x64 wave tile (acc=64)
// and __launch_bounds__(512,4); LDS 48 KiB <= 160/2.
//
// LDS: sA[2][128][32], sB[2][256][32] (bf16 bits).  Row layout: 4 slots x
// 8 bf16; slot for (row, seg) = seg ^ ((row>>1)&3) -> frag reads 2-way = free
// (m136), staging stays linear for global_load_lds (lane l: row chunk*16+l/4,
// slot l&3, fetches global seg (l&3)^((l>>3)&3)).
//
// Schedule per K-tile kt (2 phases), buffers buf=kt&1:
//  p0: read a[0..3]=A(kt), b0,b1=B(kt); STAGE_B(kt+1)->nbuf (2 loads/wave);
//      BAR; lgkm0; 8 MFMA (acc[i][0,1]); BAR.
//  p1: read b2,b3=B(kt); STAGE_A(kt+2)->buf (1 load/wave; region's last read
//      was kt.p0, all-waves-done at kt.p0 exit barrier); 8 MFMA (acc[i][2,3]);
//      VMCNT; BAR.
// vmcnt proof (loads/wave: A=1, B=2): issue order ... A(kt+1)@kt-1.p1,
//  B(kt+1)@kt.p0, A(kt+2)@kt.p1.  Wait at end kt.p1 must cover B(kt+1)
//  (newest-but-one) => vmcnt(1) (keeps A(kt+2) in flight).  Never drains to 0
//  until the tail (last 2 tiles).  Cross-wave safety: each wave's vmcnt
//  precedes the exit barrier; dependent ds_reads follow it.
// ---------------------------------------------------------------------------
#define LGKM0() do { asm volatile("s_waitcnt lgkmcnt(0)" ::: "memory"); \
                     __builtin_amdgcn_sched_barrier(0); } while (0)
#define VMCNT(n) do { asm volatile("s_waitcnt vmcnt(" #n ")" ::: "memory"); \
                      __builtin_amdgcn_sched_barrier(0); } while (0)

__global__ __launch_bounds__(512, 4) void gemm_kernel(
    const unsigned short* __restrict__ A,   // [M_DIM][IN_F] bf16 bits
    const unsigned short* __restrict__ B,   // [OUT_F][IN_F] bf16 bits
    float* __restrict__ C,                  // [M_DIM][OUT_F]
    const float* __restrict__ scale_ptr) {
    constexpr int K  = IN_F;
    constexpr int N  = OUT_F;
    constexpr int NT = K / 32;              // 128 K-tiles

    __shared__ unsigned short sA[2][128][32];   // 16 KiB
    __shared__ unsigned short sB[2][256][32];   // 32 KiB

    const int tid  = threadIdx.x;
    const int wave = tid >> 6;
    const int lane = tid & 63;
    const int quad = lane >> 4;
    const int mrow = lane & 15;
    const int sw   = quad ^ ((mrow >> 1) & 3);          // frag-read slot

    // staging lane decomposition
    const int srow = lane >> 2;                         // 0..15 (row in chunk)
    const int sseg = (lane & 3) ^ ((lane >> 3) & 3);    // source k-seg

    // Block swizzle: 1376 blocks = 8 XCDs x 172 (= 4 bm-rows x 43 bn) exact.
    // A-panel per XCD = 4x128x4096x2B = 4 MB ~ L2; XCDs walk bn in step so
    // B (90 MB < L3) is HBM-fetched ~once.
    const int lin = blockIdx.x;             // 0..1375
    const int xcd = lin & 7;
    const int q   = lin >> 3;               // 0..171
    const int bm  = xcd * 4 + q / 43;       // 0..31
    const int bn  = q % 43;                 // 0..42

    const int wm = (wave >> 2) * 64;        // wave M offset in tile (0/64)
    const int wn = (wave & 3) * 64;         // wave N offset (0/64/128/192)

    const unsigned short* Ag = A + (size_t)bm * 128 * K;
    const unsigned short* Bg = B + (size_t)bn * 256 * K;

    f32x4 acc[4][4];
#pragma unroll
    for (int i = 0; i < 4; i++)
#pragma unroll
        for (int j = 0; j < 4; j++) acc[i][j] = (f32x4){0.f, 0.f, 0.f, 0.f};

    // Stage A K-tile (128x32 = 8 KiB): 1 global_load_lds per wave.
    auto STAGE_A = [&](int nb, int kb) {
        const int row = wave * 16 + srow;
        const unsigned short* src = Ag + (size_t)row * K + kb + sseg * 8;
        __builtin_amdgcn_global_load_lds(
            (const __attribute__((address_space(1))) void*)src,
            (__attribute__((address_space(3))) void*)(&sA[nb][0][0] + wave * 512),
            16, 0, 0);
    };
    // Stage B K-tile (256x32 = 16 KiB): 2 global_load_lds per wave.
    auto STAGE_B = [&](int nb, int kb) {
#pragma unroll
        for (int c = 0; c < 2; ++c) {
            const int chunk = wave * 2 + c;
            const int row = chunk * 16 + srow;
            const unsigned short* src = Bg + (size_t)row * K + kb + sseg * 8;
            __builtin_amdgcn_global_load_lds(
                (const __attribute__((address_space(1))) void*)src,
                (__attribute__((address_space(3))) void*)(&sB[nb][0][0] + chunk * 512),
                16, 0, 0);
        }
    };

    // Prologue: A(0),B(0) -> buf0, A(1) -> buf1; wait all but A(1) => vmcnt(1).
    STAGE_A(0, 0);
    STAGE_B(0, 0);
    STAGE_A(1, 32);
    VMCNT(1);
    __builtin_amdgcn_s_barrier();

    bf16x8 a[4], b0, b1, b2, b3;

#pragma unroll 2
    for (int kt = 0; kt < NT; ++kt) {
        const int  buf  = kt & 1;
        const int  nbuf = buf ^ 1;
        const bool pf1  = (kt + 1 < NT);
        const bool pf2  = (kt + 2 < NT);

        // ---- phase 0: n-frags 0,1
#pragma unroll
        for (int t = 0; t < 4; ++t)
            a[t] = *(const bf16x8*)&sA[buf][wm + t * 16 + mrow][sw * 8];
        b0 = *(const bf16x8*)&sB[buf][wn +  0 + mrow][sw * 8];
        b1 = *(const bf16x8*)&sB[buf][wn + 16 + mrow][sw * 8];
        if (pf1) STAGE_B(nbuf, (kt + 1) * 32);
        __builtin_amdgcn_s_barrier();
        LGKM0();
        __builtin_amdgcn_s_setprio(1);
#pragma unroll
        for (int t = 0; t < 4; ++t) {
            acc[t][0] = __builtin_amdgcn_mfma_f32_16x16x32_bf16(a[t], b0, acc[t][0], 0, 0, 0);
            acc[t][1] = __builtin_amdgcn_mfma_f32_16x16x32_bf16(a[t], b1, acc[t][1], 0, 0, 0);
        }
        __builtin_amdgcn_s_setprio(0);
        __builtin_amdgcn_s_barrier();

        // ---- phase 1: n-frags 2,3
        b2 = *(const bf16x8*)&sB[buf][wn + 32 + mrow][sw * 8];
        b3 = *(const bf16x8*)&sB[buf][wn + 48 + mrow][sw * 8];
        if (pf2) STAGE_A(buf, (kt + 2) * 32);
        __builtin_amdgcn_s_barrier();
        LGKM0();
        __builtin_amdgcn_s_setprio(1);
#pragma unroll
        for (int t = 0; t < 4; ++t) {
            acc[t][2] = __builtin_amdgcn_mfma_f32_16x16x32_bf16(a[t], b2, acc[t][2], 0, 0, 0);
            acc[t][3] = __builtin_amdgcn_mfma_f32_16x16x32_bf16(a[t], b3, acc[t][3], 0, 0, 0);
        }
        __builtin_amdgcn_s_setprio(0);
        if (pf2) { VMCNT(1); } else { VMCNT(0); }   // cover B(kt+1) [+A(kt+1)]
        __builtin_amdgcn_s_barrier();
    }

    // Epilogue: C/D layout col=lane&15, row=quad*4+reg
    const float scale = *scale_ptr;
    float* Cg = C + (size_t)(bm * 128 + wm) * N + bn * 256 + wn;
#pragma unroll
    for (int i = 0; i < 4; ++i) {
#pragma unroll
        for (int j = 0; j < 4; ++j) {
#pragma unroll
            for (int r = 0; r < 4; ++r) {
                const int row = i * 16 + quad * 4 + r;
                const int col = j * 16 + mrow;
                Cg[(size_t)row * N + col] = acc[i][j][r] * scale;
            }
        }
    }
}

// ---------------------------------------------------------------------------
// Launch
// ---------------------------------------------------------------------------
extern "C" void kernel_launch(void* const* d_in, const int* in_sizes, int n_in,
                              void* d_out, int out_size, void* d_ws, size_t ws_size,
                              hipStream_t stream) {
    const float* x   = (const float*)d_in[0];     // [4,1024,4096] fp32
    const int* pw    = (const int*)d_in[1];       // [11008*4096/4] int32
    const float* wsc = (const float*)d_in[2];     // [1] fp32

    float* out = (float*)d_out;                   // [4,1024,11008] fp32

    unsigned short* xb = (unsigned short*)d_ws;
    unsigned short* wb = (unsigned short*)((char*)d_ws + (size_t)M_DIM * IN_F * 2);

    // fused prep: 8192 cvt blocks + 11008 unpack blocks
    prep_kernel<<<8192 + 11008, 256, 0, stream>>>(x, xb, pw, wb);

    // GEMM: 1376 tiles = 32 (M/128) x 43 (N/256), 512 threads, 2 blocks/CU
    gemm_kernel<<<1376, 512, 0, stream>>>(xb, wb, out, wsc);
}

// Round 4
// 602.969 us; speedup vs baseline: 1.1286x; 1.1286x over previous
//
#include <hip/hip_runtime.h>
#include <hip/hip_bf16.h>

// Problem constants
#define OUT_F 11008   // N
#define IN_F  4096    // K
#define M_DIM 4096    // 4 * 1024

typedef __attribute__((ext_vector_type(8))) short bf16x8;          // MFMA A/B frag
typedef __attribute__((ext_vector_type(4))) float f32x4;           // MFMA C/D frag
typedef __attribute__((ext_vector_type(8))) unsigned short us8;    // 16B of bf16 bits

// ---------------------------------------------------------------------------
// Kernel 1 (fused prep): blocks [0,8192) convert x fp32->bf16 (8 elems/thr);
// blocks [8192, 8192+11008) unpack 2-bit weights -> bf16 [OUT_F][IN_F].
// ---------------------------------------------------------------------------
__device__ __forceinline__ unsigned short f2bf_rne(float f) {
    unsigned u = __builtin_bit_cast(unsigned, f);
    u += 0x7fffu + ((u >> 16) & 1u);
    return (unsigned short)(u >> 16);
}

__global__ void prep_kernel(const float* __restrict__ x,
                            unsigned short* __restrict__ xb,
                            const int* __restrict__ pw,
                            unsigned short* __restrict__ wb) {
    if (blockIdx.x < 8192) {
        size_t i = ((size_t)blockIdx.x * blockDim.x + threadIdx.x) * 8;
        float4 a = *(const float4*)(x + i);
        float4 b = *(const float4*)(x + i + 4);
        us8 o;
        o[0] = f2bf_rne(a.x); o[1] = f2bf_rne(a.y);
        o[2] = f2bf_rne(a.z); o[3] = f2bf_rne(a.w);
        o[4] = f2bf_rne(b.x); o[5] = f2bf_rne(b.y);
        o[6] = f2bf_rne(b.z); o[7] = f2bf_rne(b.w);
        *(us8*)(xb + i) = o;
    } else {
        size_t i = ((size_t)(blockIdx.x - 8192)) * blockDim.x + threadIdx.x;
        int4 v = ((const int4*)pw)[i];
        const unsigned long long LUT = 0x40003F800000BF80ull;
        us8 o0, o1;
#pragma unroll
        for (int j = 0; j < 4; j++) {
            o0[j]     = (unsigned short)(LUT >> (((v.x >> (2 * j)) & 3) * 16));
            o0[4 + j] = (unsigned short)(LUT >> (((v.y >> (2 * j)) & 3) * 16));
            o1[j]     = (unsigned short)(LUT >> (((v.z >> (2 * j)) & 3) * 16));
            o1[4 + j] = (unsigned short)(LUT >> (((v.w >> (2 * j)) & 3) * 16));
        }
        ((us8*)wb)[i * 2]     = o0;
        ((us8*)wb)[i * 2 + 1] = o1;
    }
}

// ---------------------------------------------------------------------------
// Kernel 2: bf16 GEMM, 256x256 tile, BK=64, 8 waves (2x4 of 128x64),
// SINGLE-PHASE K-loop: one barrier per K-tile, no manual waitcnt.
//
// Round-4 theory: the 8-phase/8-barrier structure serialized each phase's
// LDS-read burst against its MFMA burst (measured ~2350 cyc/K-tile of
// barrier overhead = 45%).  A straight-line K-tile body lets the compiler
// interleave 24 ds_read_b128 with 64 MFMA via fine-grained lgkmcnt (m97),
// and the compiler-emitted vmcnt(0) before the single s_barrier drains the
// staging queue after ~2400 cyc of cover (>> 900-cyc HBM miss) -- the m97
// "barrier drain" stall does not apply at this issue->drain distance.
//
// Hazards with ONE barrier per K-tile:
//  - RAW (stage kt's data, read at kt): stages for kt issued during kt-1;
//    compiler vmcnt(0)+lgkmcnt(0) before barrier(kt-1), all waves => landed.
//  - WAR (stage into nbuf at kt vs reads of nbuf at kt-1): barrier(kt-1)
//    separates; each wave's ds_reads are consumed (lgkm-drained) before it.
//
// LDS: lds[buf 2][mat A/B][khalf 2][row 256][4 slots x 8 bf16] = 128 KiB.
//  - slot for (row, seg) = seg ^ ((row>>1)&3); frag reads 2-way = free (m136).
//  - Staging (global_load_lds, linear dest = base + lane*16): lane l covers
//    row chunk*16 + l/4, slot l&3 => fetch global seg (l&3)^((l>>3)&3).
// ---------------------------------------------------------------------------
__global__ __launch_bounds__(512, 2) void gemm_kernel(
    const unsigned short* __restrict__ A,   // [M_DIM][IN_F] bf16 bits
    const unsigned short* __restrict__ B,   // [OUT_F][IN_F] bf16 bits
    float* __restrict__ C,                  // [M_DIM][OUT_F]
    const float* __restrict__ scale_ptr) {
    constexpr int K  = IN_F;
    constexpr int N  = OUT_F;
    constexpr int NT = K / 64;              // 64 K-tiles

    __shared__ unsigned short lds[2][2][2][256][32];   // 128 KiB

    const int tid  = threadIdx.x;
    const int wave = tid >> 6;
    const int lane = tid & 63;
    const int quad = lane >> 4;
    const int mrow = lane & 15;
    const int sw   = quad ^ ((mrow >> 1) & 3);          // frag-read slot

    // staging lane decomposition
    const int srow = lane >> 2;                         // 0..15 (row in chunk)
    const int sseg = (lane & 3) ^ ((lane >> 3) & 3);    // source k-seg

    // Block swizzle: XCD x owns 86 consecutive tiles = 2 bm-rows x 43 bn.
    // A-panels (2x2MB) stay L2-resident per XCD; all XCDs walk bn in step so
    // B (90MB < L3) is HBM-fetched ~once. 688 % 8 == 0 => bijective.
    const int lin = blockIdx.x;             // 0..687
    const int xcd = lin & 7;
    const int q   = lin >> 3;               // 0..85
    const int bm  = xcd * 2 + q / 43;       // 0..15
    const int bn  = q % 43;                 // 0..42

    const int wm = (wave >> 2) * 128;       // wave M offset in tile
    const int wn = (wave & 3) * 64;         // wave N offset in tile

    const unsigned short* Ag = A + (size_t)bm * 256 * K;
    const unsigned short* Bg = B + (size_t)bn * 256 * K;

    f32x4 acc[8][4];
#pragma unroll
    for (int i = 0; i < 8; i++)
#pragma unroll
        for (int j = 0; j < 4; j++) acc[i][j] = (f32x4){0.f, 0.f, 0.f, 0.f};

    // Stage one half-tile slot (mat, khalf) of the K-tile at k-elem kbase
    // into buffer nb. 2 x global_load_lds (16B) per wave.
    auto STAGE = [&](int mat, int nb, int h, int kbase) {
#pragma unroll
        for (int c = 0; c < 2; ++c) {
            const int chunk = wave * 2 + c;
            const int grow  = chunk * 16 + srow;
            const unsigned short* src =
                (mat ? Bg : Ag) + (size_t)grow * K + kbase + sseg * 8;
            __builtin_amdgcn_global_load_lds(
                (const __attribute__((address_space(1))) void*)src,
                (__attribute__((address_space(3))) void*)
                    (&lds[nb][mat][h][0][0] + chunk * 512),
                16, 0, 0);
        }
    };

    // Prologue: stage K-tile 0 fully into buf0.
    STAGE(0, 0, 0, 0);     // A khalf0
    STAGE(1, 0, 0, 0);     // B khalf0
    STAGE(0, 0, 1, 32);    // A khalf1
    STAGE(1, 0, 1, 32);    // B khalf1
    __syncthreads();       // compiler emits vmcnt(0) drain

    for (int kt = 0; kt < NT; ++kt) {
        const int  buf  = kt & 1;
        const int  nbuf = buf ^ 1;
        const bool pf   = (kt + 1 < NT);
        const int  kn   = (kt + 1) * 64;

        // Issue next tile's staging first: maximal issue->drain distance.
        if (pf) {
            STAGE(0, nbuf, 0, kn);
            STAGE(1, nbuf, 0, kn);
            STAGE(0, nbuf, 1, kn + 32);
            STAGE(1, nbuf, 1, kn + 32);
        }

        // Straight-line compute body: compiler interleaves ds_read/MFMA.
#pragma unroll
        for (int h = 0; h < 2; ++h) {
            bf16x8 a[8], b[4];
#pragma unroll
            for (int t = 0; t < 8; ++t)
                a[t] = *(const bf16x8*)&lds[buf][0][h][wm + t * 16 + mrow][sw * 8];
#pragma unroll
            for (int j = 0; j < 4; ++j)
                b[j] = *(const bf16x8*)&lds[buf][1][h][wn + j * 16 + mrow][sw * 8];
#pragma unroll
            for (int t = 0; t < 8; ++t)
#pragma unroll
                for (int j = 0; j < 4; ++j)
                    acc[t][j] = __builtin_amdgcn_mfma_f32_16x16x32_bf16(
                        a[t], b[j], acc[t][j], 0, 0, 0);
        }

        __syncthreads();   // one barrier per K-tile (vmcnt+lgkm drain implied)
    }

    // Epilogue: C/D layout col=lane&15, row=quad*4+reg
    const float scale = *scale_ptr;
    float* Cg = C + (size_t)(bm * 256 + wm) * N + bn * 256 + wn;
#pragma unroll
    for (int i = 0; i < 8; ++i) {
#pragma unroll
        for (int j = 0; j < 4; ++j) {
#pragma unroll
            for (int r = 0; r < 4; ++r) {
                const int row = i * 16 + quad * 4 + r;
                const int col = j * 16 + mrow;
                Cg[(size_t)row * N + col] = acc[i][j][r] * scale;
            }
        }
    }
}

// ---------------------------------------------------------------------------
// Launch
// ---------------------------------------------------------------------------
extern "C" void kernel_launch(void* const* d_in, const int* in_sizes, int n_in,
                              void* d_out, int out_size, void* d_ws, size_t ws_size,
                              hipStream_t stream) {
    const float* x   = (const float*)d_in[0];     // [4,1024,4096] fp32
    const int* pw    = (const int*)d_in[1];       // [11008*4096/4] int32
    const float* wsc = (const float*)d_in[2];     // [1] fp32

    float* out = (float*)d_out;                   // [4,1024,11008] fp32

    unsigned short* xb = (unsigned short*)d_ws;
    unsigned short* wb = (unsigned short*)((char*)d_ws + (size_t)M_DIM * IN_F * 2);

    // fused prep: 8192 cvt blocks + 11008 unpack blocks
    prep_kernel<<<8192 + 11008, 256, 0, stream>>>(x, xb, pw, wb);

    // GEMM: 688 tiles = 16 (M/256) x 43 (N/256), 512 threads (8 waves)
    gemm_kernel<<<688, 512, 0, stream>>>(xb, wb, out, wsc);
}